// Round 5
// baseline (1258.736 us; speedup 1.0000x reference)
//
#include <hip/hip_runtime.h>

// dfm: 10-feature FM layer. x_i are dense one-hot (1024 x v_i) fp32; w_i (v_i x 64) fp32.
// out (1024 x 704) fp32 = [0.5*(sum(emb)^2 - sum(emb^2)) | emb0 .. emb9]
// One-hot => dot(x,w) == val*w[idx] exactly; dot(x^2,w^2) == val^2*w[idx]^2.
//
// R4: R2's byte-lean wave allocation (f0/f1: 4 waves/row; f2..f9: 1 wave/row)
// + fused emit: per-row completion counter (agent-scope atomics); the wave
// completing the 10th feature of a row emits that row. Single scan dispatch
// + 4KB memset. Removes the separate emit kernel's launch gap and overlaps
// the w-gather with the scan tail.

#define NF 10
#define BATCHN 1024
#define EMBD 64

constexpr int VOC[NF] = {100000, 50000, 20000, 10000, 5000, 2000, 1000, 500, 200, 100};
// all VOC divisible by 4 -> float4 loads never straddle the row end

struct XPtrs { const float* x[NF]; };
struct WPtrs { const float* w[NF]; };

typedef float v4f __attribute__((ext_vector_type(4)));

__device__ __forceinline__ v4f ntload4(const float* p) {
  return __builtin_nontemporal_load(reinterpret_cast<const v4f*>(p));
}

// Scans one 4KB chunk (1024 floats at j0): 4 x float4 per lane, 256 floats apart.
// Returns wave-uniform "found"; finder lane publishes (idx,val) agent-scope.
__device__ __forceinline__ bool scan_chunk(const float* rp, int v, int j0, int lane,
                                           int slot, int* __restrict__ idx_out,
                                           float* __restrict__ val_out) {
  v4f q[4];
#pragma unroll
  for (int s = 0; s < 4; ++s) {
    const int j = j0 + s * 256 + lane * 4;
    if (j < v) q[s] = ntload4(rp + j);
    else       q[s] = (v4f){0.f, 0.f, 0.f, 0.f};
  }
  bool flag = false;
#pragma unroll
  for (int s = 0; s < 4; ++s)
    flag |= (q[s][0] != 0.f) | (q[s][1] != 0.f) | (q[s][2] != 0.f) | (q[s][3] != 0.f);
  if (__ballot(flag)) {
    if (flag) {
#pragma unroll
      for (int s = 0; s < 4; ++s) {
#pragma unroll
        for (int c = 0; c < 4; ++c) {
          if (q[s][c] != 0.f) {
            __hip_atomic_store(&idx_out[slot], j0 + s * 256 + lane * 4 + c,
                               __ATOMIC_RELEASE, __HIP_MEMORY_SCOPE_AGENT);
            __hip_atomic_store(&val_out[slot], q[s][c],
                               __ATOMIC_RELEASE, __HIP_MEMORY_SCOPE_AGENT);
          }
        }
      }
    }
    return true;
  }
  return false;
}

// Emits one output row (the whole wave; lane = emb dim). Reads all 10 (idx,val)
// agent-scope (writers may be on other XCDs), gathers w rows, FM trick.
__device__ __forceinline__ void emit_row(WPtrs wp, const int* __restrict__ idx,
                                         const float* __restrict__ val,
                                         float* __restrict__ out, int row, int lane) {
  float s = 0.f, q = 0.f, e[NF];
#pragma unroll
  for (int f = 0; f < NF; ++f) {
    const int   ix = __hip_atomic_load(&idx[f * BATCHN + row],
                                       __ATOMIC_ACQUIRE, __HIP_MEMORY_SCOPE_AGENT);
    const float vv = __hip_atomic_load(&val[f * BATCHN + row],
                                       __ATOMIC_ACQUIRE, __HIP_MEMORY_SCOPE_AGENT);
    const float wv = wp.w[f][(size_t)ix * EMBD + lane];
    const float ev = vv * wv;
    e[f] = ev;
    s += ev;
    q += (vv * vv) * (wv * wv);   // x^2 . w^2
  }
  float* o = out + (size_t)row * ((NF + 1) * EMBD);
  o[lane] = 0.5f * (s * s - q);
#pragma unroll
  for (int f = 0; f < NF; ++f)
    o[(f + 1) * EMBD + lane] = e[f];
}

// Finder-wave completion: bump the row counter; the 10th completer emits.
__device__ __forceinline__ void complete(WPtrs wp, int* __restrict__ cnt,
                                         const int* __restrict__ idx,
                                         const float* __restrict__ val,
                                         float* __restrict__ out, int row, int lane) {
  __threadfence();                       // release: idx/val visible before count
  int old = 0;
  if (lane == 0) old = atomicAdd(&cnt[row], 1);
  old = __shfl(old, 0);
  if (old == NF - 1) {
    __threadfence();                     // acquire side
    emit_row(wp, idx, val, out, row, lane);
  }
}

// W waves cooperatively scan one row of feature F; early exit via volatile LDS flag.
// Returns true iff THIS wave found the nonzero.
template <int F, int W>
__device__ __forceinline__ bool scan_multi(const float* __restrict__ xbase, int row,
                                           int w, int lane, volatile int* flag,
                                           int* __restrict__ idx_out,
                                           float* __restrict__ val_out) {
  const int v   = VOC[F];
  const int nch = (v + 1023) >> 10;
  const float* rp = xbase + (size_t)row * v;
  const int slot = F * BATCHN + row;
  for (int k = w; k < nch; k += W) {
    if (W > 1 && *flag) return false;    // sibling wave found it
    if (scan_chunk(rp, v, k << 10, lane, slot, idx_out, val_out)) {
      *flag = 1;
      return true;
    }
  }
  return false;
}

// Single wave scans one row of feature F.
template <int F>
__device__ __forceinline__ bool scan_wave(const float* __restrict__ xbase, int row,
                                          int lane, int* __restrict__ idx_out,
                                          float* __restrict__ val_out) {
  const int v   = VOC[F];
  const int nch = (v + 1023) >> 10;
  const float* rp = xbase + (size_t)row * v;
  const int slot = F * BATCHN + row;
  for (int k = 0; k < nch; ++k)
    if (scan_chunk(rp, v, k << 10, lane, slot, idx_out, val_out)) return true;
  return false;
}

#define NBIG 2
#define BIG_BLOCKS (NBIG * BATCHN)                  // 2048
#define SMALL_BLOCKS ((NF - NBIG) * BATCHN / 4)     // 2048
#define TOTAL_BLOCKS (BIG_BLOCKS + SMALL_BLOCKS)    // 4096

__global__ __launch_bounds__(256) void scan_fused(XPtrs xp, WPtrs wp,
                                                  int* __restrict__ idx,
                                                  float* __restrict__ val,
                                                  int* __restrict__ cnt,
                                                  float* __restrict__ out) {
  const int blk  = blockIdx.x;
  const int tid  = threadIdx.x;
  const int wid  = tid >> 6;
  const int lane = tid & 63;

  __shared__ volatile int done;

  if (blk < BIG_BLOCKS) {
    if (tid == 0) done = 0;
    __syncthreads();
    const int row = blk & 1023;
    bool found;
    if (blk < BATCHN) found = scan_multi<0, 4>(xp.x[0], row, wid, lane, &done, idx, val);
    else              found = scan_multi<1, 4>(xp.x[1], row, wid, lane, &done, idx, val);
    if (found) complete(wp, cnt, idx, val, out, row, lane);
  } else {
    // wave-per-row: widx in [0, 8192), feature f = 2 + widx>>10, row = widx & 1023
    const int widx = ((blk - BIG_BLOCKS) << 2) + wid;
    const int f    = NBIG + (widx >> 10);
    const int row  = widx & 1023;
    bool found = false;
    switch (f) {
      case 2: found = scan_wave<2>(xp.x[2], row, lane, idx, val); break;
      case 3: found = scan_wave<3>(xp.x[3], row, lane, idx, val); break;
      case 4: found = scan_wave<4>(xp.x[4], row, lane, idx, val); break;
      case 5: found = scan_wave<5>(xp.x[5], row, lane, idx, val); break;
      case 6: found = scan_wave<6>(xp.x[6], row, lane, idx, val); break;
      case 7: found = scan_wave<7>(xp.x[7], row, lane, idx, val); break;
      case 8: found = scan_wave<8>(xp.x[8], row, lane, idx, val); break;
      case 9: found = scan_wave<9>(xp.x[9], row, lane, idx, val); break;
    }
    if (found) complete(wp, cnt, idx, val, out, row, lane);
  }
}

extern "C" void kernel_launch(void* const* d_in, const int* in_sizes, int n_in,
                              void* d_out, int out_size, void* d_ws, size_t ws_size,
                              hipStream_t stream) {
  XPtrs xp;
  WPtrs wp;
  for (int i = 0; i < NF; ++i) {
    xp.x[i] = (const float*)d_in[2 * i];       // x_i
    wp.w[i] = (const float*)d_in[2 * i + 1];   // w_i
  }
  int*   idx = (int*)d_ws;
  float* val = (float*)((char*)d_ws + (size_t)NF * BATCHN * sizeof(int));
  int*   cnt = (int*)((char*)d_ws + (size_t)2 * NF * BATCHN * sizeof(int));

  hipMemsetAsync(cnt, 0, BATCHN * sizeof(int), stream);   // graph-capturable
  scan_fused<<<TOTAL_BLOCKS, 256, 0, stream>>>(xp, wp, idx, val, cnt, (float*)d_out);
}

// Round 6
// 91.419 us; speedup vs baseline: 13.7689x; 13.7689x over previous
//
#include <hip/hip_runtime.h>

// dfm: 10-feature FM layer. x_i are dense one-hot (1024 x v_i) fp32; w_i (v_i x 64) fp32.
// out (1024 x 704) fp32 = [0.5*(sum(emb)^2 - sum(emb^2)) | emb0 .. emb9]
// One-hot => dot(x,w) == val*w[idx] exactly; dot(x^2,w^2) == val^2*w[idx]^2 == emb^2
// (exact because one-hot val == 1.0f), so FM needs only the embeddings.
//
// R5: R2's byte-lean scan (f0/f1: 4 waves/row; f2..f9: 1 wave/row) with the
// finder wave emitting its embedding DIRECTLY to out (ballot+shfl broadcast,
// coalesced 64-lane w-row gather). No ws handoff, no atomics, no fences
// (R4's per-wave __threadfence caused L2-writeback serialization: 1.26 ms).
// A tiny combine kernel then computes fm from the 10 embeddings per row
// (kernel-boundary coherence makes the scan's writes visible; mostly L2 hits).

#define NF 10
#define BATCHN 1024
#define EMBD 64
#define OUTW ((NF + 1) * EMBD)   // 704

constexpr int VOC[NF] = {100000, 50000, 20000, 10000, 5000, 2000, 1000, 500, 200, 100};
// all VOC divisible by 4 -> float4 loads never straddle the row end

struct XPtrs { const float* x[NF]; };
struct WPtrs { const float* w[NF]; };

typedef float v4f __attribute__((ext_vector_type(4)));

__device__ __forceinline__ v4f ntload4(const float* p) {
  return __builtin_nontemporal_load(reinterpret_cast<const v4f*>(p));
}

// Scans one 4KB chunk (1024 floats at j0): 4 x float4 per lane, 256 floats apart.
// If the nonzero is in this chunk: broadcast (idx,val) wave-wide, gather the
// w row (lane = emb dim, coalesced 256B), store emb to out. Returns found.
__device__ __forceinline__ bool scan_chunk(const float* rp, int v, int j0, int lane,
                                           const float* __restrict__ wf,
                                           float* __restrict__ dst) {
  v4f q[4];
#pragma unroll
  for (int s = 0; s < 4; ++s) {
    const int j = j0 + s * 256 + lane * 4;
    if (j < v) q[s] = ntload4(rp + j);
    else       q[s] = (v4f){0.f, 0.f, 0.f, 0.f};
  }
  int   local = -1;
  float lval  = 0.f;
#pragma unroll
  for (int s = 0; s < 4; ++s) {
#pragma unroll
    for (int c = 0; c < 4; ++c) {
      if (q[s][c] != 0.f) { local = j0 + s * 256 + lane * 4 + c; lval = q[s][c]; }
    }
  }
  const unsigned long long m = __ballot(local >= 0);
  if (m) {
    const int   src = (int)__ffsll(m) - 1;      // the (single) finder lane
    const int   ix  = __shfl(local, src);
    const float vv  = __shfl(lval, src);
    dst[lane] = vv * wf[(size_t)ix * EMBD + lane];
    return true;
  }
  return false;
}

// W waves cooperatively scan one row of feature F; early exit via volatile LDS flag.
template <int F, int W>
__device__ __forceinline__ void scan_multi(const float* __restrict__ xbase, int row,
                                           int w, int lane, volatile int* flag,
                                           const float* __restrict__ wf,
                                           float* __restrict__ out) {
  const int v   = VOC[F];
  const int nch = (v + 1023) >> 10;
  const float* rp = xbase + (size_t)row * v;
  float* dst = out + (size_t)row * OUTW + (F + 1) * EMBD;
  for (int k = w; k < nch; k += W) {
    if (scan_chunk(rp, v, k << 10, lane, wf, dst)) {
      *flag = 1;
      return;
    }
    if (*flag) return;            // sibling wave found it
  }
}

// Single wave scans one row of feature F.
template <int F>
__device__ __forceinline__ void scan_wave(const float* __restrict__ xbase, int row,
                                          int lane, const float* __restrict__ wf,
                                          float* __restrict__ out) {
  const int v   = VOC[F];
  const int nch = (v + 1023) >> 10;
  const float* rp = xbase + (size_t)row * v;
  float* dst = out + (size_t)row * OUTW + (F + 1) * EMBD;
  for (int k = 0; k < nch; ++k)
    if (scan_chunk(rp, v, k << 10, lane, wf, dst)) return;
}

#define NBIG 2
#define BIG_BLOCKS (NBIG * BATCHN)                  // 2048
#define SMALL_BLOCKS ((NF - NBIG) * BATCHN / 4)     // 2048
#define TOTAL_BLOCKS (BIG_BLOCKS + SMALL_BLOCKS)    // 4096

__global__ __launch_bounds__(256) void scan_emit(XPtrs xp, WPtrs wp,
                                                 float* __restrict__ out) {
  const int blk  = blockIdx.x;
  const int tid  = threadIdx.x;
  const int wid  = tid >> 6;
  const int lane = tid & 63;

  __shared__ volatile int done;

  if (blk < BIG_BLOCKS) {
    if (tid == 0) done = 0;
    __syncthreads();
    const int row = blk & 1023;
    if (blk < BATCHN) scan_multi<0, 4>(xp.x[0], row, wid, lane, &done, wp.w[0], out);
    else              scan_multi<1, 4>(xp.x[1], row, wid, lane, &done, wp.w[1], out);
  } else {
    // wave-per-row: widx in [0, 8192), feature f = 2 + widx>>10, row = widx & 1023
    const int widx = ((blk - BIG_BLOCKS) << 2) + wid;
    const int f    = NBIG + (widx >> 10);
    const int row  = widx & 1023;
    switch (f) {
      case 2: scan_wave<2>(xp.x[2], row, lane, wp.w[2], out); break;
      case 3: scan_wave<3>(xp.x[3], row, lane, wp.w[3], out); break;
      case 4: scan_wave<4>(xp.x[4], row, lane, wp.w[4], out); break;
      case 5: scan_wave<5>(xp.x[5], row, lane, wp.w[5], out); break;
      case 6: scan_wave<6>(xp.x[6], row, lane, wp.w[6], out); break;
      case 7: scan_wave<7>(xp.x[7], row, lane, wp.w[7], out); break;
      case 8: scan_wave<8>(xp.x[8], row, lane, wp.w[8], out); break;
      case 9: scan_wave<9>(xp.x[9], row, lane, wp.w[9], out); break;
    }
  }
}

// One wave per row (4 rows/block): fm = 0.5*((sum_f e_f)^2 - sum_f e_f^2).
// Sequential f order matches the reference accumulation order; e_f^2 ==
// vv^2*wv^2 exactly since the one-hot value is exactly 1.0f.
__global__ __launch_bounds__(256) void fm_combine(float* __restrict__ out) {
  const int row  = blockIdx.x * 4 + (threadIdx.x >> 6);
  const int lane = threadIdx.x & 63;
  float* o = out + (size_t)row * OUTW;
  float s = 0.f, q = 0.f;
#pragma unroll
  for (int f = 0; f < NF; ++f) {
    const float e = o[(f + 1) * EMBD + lane];
    s += e;
    q += e * e;
  }
  o[lane] = 0.5f * (s * s - q);
}

extern "C" void kernel_launch(void* const* d_in, const int* in_sizes, int n_in,
                              void* d_out, int out_size, void* d_ws, size_t ws_size,
                              hipStream_t stream) {
  XPtrs xp;
  WPtrs wp;
  for (int i = 0; i < NF; ++i) {
    xp.x[i] = (const float*)d_in[2 * i];       // x_i
    wp.w[i] = (const float*)d_in[2 * i + 1];   // w_i
  }
  scan_emit<<<TOTAL_BLOCKS, 256, 0, stream>>>(xp, wp, (float*)d_out);
  fm_combine<<<BATCHN / 4, 256, 0, stream>>>((float*)d_out);
}

// Round 7
// 85.862 us; speedup vs baseline: 14.6600x; 1.0647x over previous
//
#include <hip/hip_runtime.h>

// dfm: 10-feature FM layer. x_i are dense one-hot (1024 x v_i) fp32; w_i (v_i x 64) fp32.
// out (1024 x 704) fp32 = [0.5*(sum(emb)^2 - sum(emb^2)) | emb0 .. emb9]
// One-hot => dot(x,w) == val*w[idx] exactly; dot(x^2,w^2) == val^2*w[idx]^2.
//
// R6 = R2 champion structure (77 us) + two strict-subtraction micro-opts:
//  - scan: integer OR-reduce for the common-path "any nonzero?" check
//    (~22 VALU/lane/chunk vs ~35); found-branch does position extraction.
//  - emit: 4 waves/block (256 blocks) instead of 1024 x 64-thread blocks.
// Structure (proven best): f0/f1 4 waves/row w/ volatile-LDS flag; f2..f9
// wave-per-row w/ __ballot exit; idx/val handoff through ws; separate emit
// kernel behind the kernel-boundary coherence point. No atomics, no fences
// (R4: per-wave __threadfence collapsed BW to 175 GB/s). No emit-in-scan
// (R5: +14 us from hot-loop VALU + exit-path gather).

#define NF 10
#define BATCHN 1024
#define EMBD 64
#define OUTW ((NF + 1) * EMBD)   // 704

constexpr int VOC[NF] = {100000, 50000, 20000, 10000, 5000, 2000, 1000, 500, 200, 100};
// all VOC divisible by 4 -> float4 loads never straddle the row end

struct XPtrs { const float* x[NF]; };
struct WPtrs { const float* w[NF]; };

typedef float v4f __attribute__((ext_vector_type(4)));
typedef int   v4i __attribute__((ext_vector_type(4)));

__device__ __forceinline__ v4f ntload4(const float* p) {
  return __builtin_nontemporal_load(reinterpret_cast<const v4f*>(p));
}

// Scans one 4KB chunk (1024 floats at j0): 4 x float4 per lane, 256 floats apart.
// Common path: OR-reduce the 16 words -> 1 compare -> ballot. Found path only:
// locate the nonzero, write (idx,val). Exactly one nonzero per row -> one writer.
__device__ __forceinline__ bool scan_chunk(const float* rp, int v, int j0, int lane,
                                           int slot, int* __restrict__ idx_out,
                                           float* __restrict__ val_out) {
  v4f q[4];
#pragma unroll
  for (int s = 0; s < 4; ++s) {
    const int j = j0 + s * 256 + lane * 4;
    if (j < v) q[s] = ntload4(rp + j);
    else       q[s] = (v4f){0.f, 0.f, 0.f, 0.f};
  }
  int acc = 0;
#pragma unroll
  for (int s = 0; s < 4; ++s) {
    const v4i b = __builtin_bit_cast(v4i, q[s]);
    acc |= b[0] | b[1] | b[2] | b[3];    // one-hot vals are +1.0f: no -0.0 issue
  }
  if (__ballot(acc != 0)) {
    if (acc != 0) {
#pragma unroll
      for (int s = 0; s < 4; ++s) {
#pragma unroll
        for (int c = 0; c < 4; ++c) {
          if (q[s][c] != 0.f) {
            idx_out[slot] = j0 + s * 256 + lane * 4 + c;
            val_out[slot] = q[s][c];
          }
        }
      }
    }
    return true;
  }
  return false;
}

// W waves cooperatively scan one row of feature F; early exit via volatile LDS flag.
template <int F, int W>
__device__ __forceinline__ void scan_multi(const float* __restrict__ xbase, int row,
                                           int w, int lane, volatile int* flag,
                                           int* __restrict__ idx_out,
                                           float* __restrict__ val_out) {
  const int v   = VOC[F];
  const int nch = (v + 1023) >> 10;
  const float* rp = xbase + (size_t)row * v;
  const int slot = F * BATCHN + row;
  for (int k = w; k < nch; k += W) {
    if (scan_chunk(rp, v, k << 10, lane, slot, idx_out, val_out)) {
      *flag = 1;
      return;
    }
    if (*flag) return;            // sibling wave found it
  }
}

// Single wave scans one row of feature F.
template <int F>
__device__ __forceinline__ void scan_wave(const float* __restrict__ xbase, int row,
                                          int lane, int* __restrict__ idx_out,
                                          float* __restrict__ val_out) {
  const int v   = VOC[F];
  const int nch = (v + 1023) >> 10;
  const float* rp = xbase + (size_t)row * v;
  const int slot = F * BATCHN + row;
  for (int k = 0; k < nch; ++k)
    if (scan_chunk(rp, v, k << 10, lane, slot, idx_out, val_out)) return;
}

#define NBIG 2
#define BIG_BLOCKS (NBIG * BATCHN)                  // 2048
#define SMALL_BLOCKS ((NF - NBIG) * BATCHN / 4)     // 2048
#define TOTAL_BLOCKS (BIG_BLOCKS + SMALL_BLOCKS)    // 4096

__global__ __launch_bounds__(256) void scan_onehot(XPtrs p,
                                                   int* __restrict__ idx_out,
                                                   float* __restrict__ val_out) {
  const int blk  = blockIdx.x;
  const int tid  = threadIdx.x;
  const int wid  = tid >> 6;
  const int lane = tid & 63;

  __shared__ volatile int done;

  if (blk < BIG_BLOCKS) {
    if (tid == 0) done = 0;
    __syncthreads();
    const int row = blk & 1023;
    if (blk < BATCHN) scan_multi<0, 4>(p.x[0], row, wid, lane, &done, idx_out, val_out);
    else              scan_multi<1, 4>(p.x[1], row, wid, lane, &done, idx_out, val_out);
  } else {
    // wave-per-row: widx in [0, 8192), feature f = 2 + widx>>10, row = widx & 1023
    const int widx = ((blk - BIG_BLOCKS) << 2) + wid;
    const int f    = NBIG + (widx >> 10);
    const int row  = widx & 1023;
    switch (f) {
      case 2: scan_wave<2>(p.x[2], row, lane, idx_out, val_out); break;
      case 3: scan_wave<3>(p.x[3], row, lane, idx_out, val_out); break;
      case 4: scan_wave<4>(p.x[4], row, lane, idx_out, val_out); break;
      case 5: scan_wave<5>(p.x[5], row, lane, idx_out, val_out); break;
      case 6: scan_wave<6>(p.x[6], row, lane, idx_out, val_out); break;
      case 7: scan_wave<7>(p.x[7], row, lane, idx_out, val_out); break;
      case 8: scan_wave<8>(p.x[8], row, lane, idx_out, val_out); break;
      case 9: scan_wave<9>(p.x[9], row, lane, idx_out, val_out); break;
    }
  }
}

// 4 waves/block, one row per wave (lane = emb dim). Sequential f accumulation
// matches the reference order exactly.
__global__ __launch_bounds__(256) void emit_fm(WPtrs wp,
                                               const int* __restrict__ idx,
                                               const float* __restrict__ val,
                                               float* __restrict__ out) {
  const int b = blockIdx.x * 4 + (threadIdx.x >> 6);
  const int d = threadIdx.x & 63;
  float s = 0.0f, q = 0.0f;
  float e[NF];
#pragma unroll
  for (int i = 0; i < NF; ++i) {
    const int   ix = idx[i * BATCHN + b];
    const float vv = val[i * BATCHN + b];
    const float wv = wp.w[i][(size_t)ix * EMBD + d];
    const float ev = vv * wv;
    e[i] = ev;
    s += ev;
    q += (vv * vv) * (wv * wv);   // x^2 . w^2
  }
  float* o = out + (size_t)b * OUTW;
  o[d] = 0.5f * (s * s - q);
#pragma unroll
  for (int i = 0; i < NF; ++i) {
    o[(i + 1) * EMBD + d] = e[i];
  }
}

extern "C" void kernel_launch(void* const* d_in, const int* in_sizes, int n_in,
                              void* d_out, int out_size, void* d_ws, size_t ws_size,
                              hipStream_t stream) {
  XPtrs xp;
  WPtrs wp;
  for (int i = 0; i < NF; ++i) {
    xp.x[i] = (const float*)d_in[2 * i];       // x_i
    wp.w[i] = (const float*)d_in[2 * i + 1];   // w_i
  }
  int*   idx = (int*)d_ws;
  float* val = (float*)((char*)d_ws + (size_t)NF * BATCHN * sizeof(int));

  scan_onehot<<<TOTAL_BLOCKS, 256, 0, stream>>>(xp, idx, val);
  emit_fm<<<BATCHN / 4, 256, 0, stream>>>(wp, idx, val, (float*)d_out);
}

// Round 8
// 77.351 us; speedup vs baseline: 16.2730x; 1.1100x over previous
//
#include <hip/hip_runtime.h>

// dfm: 10-feature FM layer. x_i are dense one-hot (1024 x v_i) fp32; w_i (v_i x 64) fp32.
// out (1024 x 704) fp32 = [0.5*(sum(emb)^2 - sum(emb^2)) | emb0 .. emb9]
// One-hot => dot(x,w) == val*w[idx] exactly; dot(x^2,w^2) == val^2*w[idx]^2.
//
// R7 = exact reproduction of the R2 champion (77.0 us). Every structural
// deviation measured worse: R3 wider waves (+3.5), R4 fences (+1180),
// R5 fused emit (+14), R6 int-OR check + packed emit (+9). This is the
// byte-identical champion for reproducibility confirmation.

#define NF 10
#define BATCHN 1024
#define EMBD 64

constexpr int VOC[NF] = {100000, 50000, 20000, 10000, 5000, 2000, 1000, 500, 200, 100};
// all VOC divisible by 4 -> float4 loads never straddle the row end

struct XPtrs { const float* x[NF]; };
struct WPtrs { const float* w[NF]; };

typedef float v4f __attribute__((ext_vector_type(4)));

__device__ __forceinline__ v4f ntload4(const float* p) {
  return __builtin_nontemporal_load(reinterpret_cast<const v4f*>(p));
}

#define NBIG 2     // features with block-per-row
#define BIG_BLOCKS (NBIG * BATCHN)                  // 2048
#define SMALL_BLOCKS ((NF - NBIG) * BATCHN / 4)     // 2048
#define TOTAL_BLOCKS (BIG_BLOCKS + SMALL_BLOCKS)    // 4096

// Scans one chunk's 16 floats (4 x float4 sub-loads, 256 floats apart), returns flag.
// On flag, locates the nonzero and writes (idx,val). Exactly one nonzero per row.
__device__ __forceinline__ bool scan_chunk(const float* rp, int v, int j0, int lane,
                                           int slot, int* idx_out, float* val_out,
                                           bool* oflag) {
  v4f q[4];
#pragma unroll
  for (int s = 0; s < 4; ++s) {
    const int j = j0 + s * 256 + lane * 4;
    if (j < v) q[s] = ntload4(rp + j);
    else       q[s] = (v4f){0.f, 0.f, 0.f, 0.f};
  }
  bool flag = false;
#pragma unroll
  for (int s = 0; s < 4; ++s)
    flag |= (q[s][0] != 0.f) | (q[s][1] != 0.f) | (q[s][2] != 0.f) | (q[s][3] != 0.f);
  if (__ballot(flag)) {
    if (flag) {
#pragma unroll
      for (int s = 0; s < 4; ++s) {
#pragma unroll
        for (int c = 0; c < 4; ++c) {
          if (q[s][c] != 0.f) {
            idx_out[slot] = j0 + s * 256 + lane * 4 + c;
            val_out[slot] = q[s][c];
          }
        }
      }
    }
    *oflag = flag;
    return true;
  }
  *oflag = false;
  return false;
}

__global__ __launch_bounds__(256) void scan_onehot(XPtrs p,
                                                   int* __restrict__ idx_out,
                                                   float* __restrict__ val_out) {
  const int blk  = blockIdx.x;
  const int tid  = threadIdx.x;
  const int wid  = tid >> 6;
  const int lane = tid & 63;

  if (blk < BIG_BLOCKS) {
    // block-per-row: feature f = blk>>10 (0..NBIG-1), row = blk & 1023
    __shared__ volatile int done;
    if (tid == 0) done = 0;
    __syncthreads();
    const int f   = blk >> 10;
    const int row = blk & 1023;
#pragma unroll
    for (int i = 0; i < NBIG; ++i) {
      if (f == i) {
        const int v   = VOC[i];
        const int nch = (v + 1023) >> 10;
        const float* rp = p.x[i] + (size_t)row * v;
        for (int k = wid; k < nch; k += 4) {   // interleaved chunks, no barrier
          bool fl;
          if (scan_chunk(rp, v, k << 10, lane, i * BATCHN + row, idx_out, val_out, &fl)) {
            done = 1;           // all lanes of finder wave write 1 (benign)
            break;
          }
          if (done) break;      // volatile LDS poll; set by sibling wave
        }
      }
    }
  } else {
    // wave-per-row: widx in [0, 8192), feature f = 2 + widx>>10, row = widx & 1023
    const int widx = ((blk - BIG_BLOCKS) << 2) + wid;
    const int f    = NBIG + (widx >> 10);
    const int row  = widx & 1023;
#pragma unroll
    for (int i = NBIG; i < NF; ++i) {
      if (f == i) {
        const int v   = VOC[i];
        const int nch = (v + 1023) >> 10;
        const float* rp = p.x[i] + (size_t)row * v;
        for (int k = 0; k < nch; ++k) {
          bool fl;
          if (scan_chunk(rp, v, k << 10, lane, i * BATCHN + row, idx_out, val_out, &fl))
            break;
        }
      }
    }
  }
}

// grid = 1024 (one block per batch row), block = 64 (one thread per emb dim).
// Accumulation order matches the reference (sequential i = 0..9).
__global__ __launch_bounds__(64) void emit_fm(WPtrs wp,
                                              const int* __restrict__ idx,
                                              const float* __restrict__ val,
                                              float* __restrict__ out) {
  const int b = blockIdx.x;
  const int d = threadIdx.x;
  float s = 0.0f, q = 0.0f;
  float e[NF];
#pragma unroll
  for (int i = 0; i < NF; ++i) {
    const int   ix = idx[i * BATCHN + b];
    const float vv = val[i * BATCHN + b];
    const float wv = wp.w[i][(size_t)ix * EMBD + d];
    const float ev = vv * wv;
    e[i] = ev;
    s += ev;
    q += (vv * vv) * (wv * wv);   // x^2 . w^2
  }
  float* o = out + (size_t)b * ((NF + 1) * EMBD);
  o[d] = 0.5f * (s * s - q);
#pragma unroll
  for (int i = 0; i < NF; ++i) {
    o[(i + 1) * EMBD + d] = e[i];
  }
}

extern "C" void kernel_launch(void* const* d_in, const int* in_sizes, int n_in,
                              void* d_out, int out_size, void* d_ws, size_t ws_size,
                              hipStream_t stream) {
  XPtrs xp;
  WPtrs wp;
  for (int i = 0; i < NF; ++i) {
    xp.x[i] = (const float*)d_in[2 * i];       // x_i
    wp.w[i] = (const float*)d_in[2 * i + 1];   // w_i
  }
  int*   idx = (int*)d_ws;
  float* val = (float*)((char*)d_ws + (size_t)NF * BATCHN * sizeof(int));

  scan_onehot<<<TOTAL_BLOCKS, 256, 0, stream>>>(xp, idx, val);
  emit_fm<<<BATCHN, 64, 0, stream>>>(wp, idx, val, (float*)d_out);
}